// Round 9
// baseline (185.617 us; speedup 1.0000x reference)
//
#include <hip/hip_runtime.h>

// GCN 2-layer encoder for MI355X (gfx950) — round 9.
// r8 post-mortem: MFMA GEMM regressed via LDS (12.8M bank conflicts from the
// transposed-W staging: 320B thread stride = 2 banks). MfmaUtil 2.5% -> the
// MFMA work is tiny; W fits L1/L2. r9: weights pre-split ONCE (bf16 hi/lo,
// transposed [n][k], fused into k_init) -> both GEMMs are LDS-free and
// barrier-free, B-frags read straight from global. Fill slimmed: record is
// just src (4B, plain store); gathers read dinv[src] as a broadcast load.
//
// Pipeline (8 dispatches):
//   k_init(zero indeg || split W1,W2) -> k_count -> k_scan1 -> k_scan3
//   -> k_fill_gemm1(fill || mfma-gemm1) -> k_gather_relu -> k_gemm2_mfma
//   -> k_gather<64>

constexpr int IN_CH  = 128;
constexpr int HID    = 128;
constexpr int OUT_CH = 64;
constexpr int SCAN_CHUNK = 4096;

using short8v = __attribute__((ext_vector_type(8))) short;
using f32x4v  = __attribute__((ext_vector_type(4))) float;

__device__ __forceinline__ unsigned short f2bf_rne(float f) {
    unsigned int u = __float_as_uint(f);
    u += 0x7FFFu + ((u >> 16) & 1u);
    return (unsigned short)(u >> 16);
}
__device__ __forceinline__ float bf2f(unsigned short h) {
    return __uint_as_float((unsigned int)h << 16);
}

__device__ __forceinline__ bool probe_is64(const int* __restrict__ ei) {
    const int v = ei[2 * (threadIdx.x & 63) + 1];
    return __ballot(v != 0) == 0ull;
}

__device__ __forceinline__ void load_idx4(const int* __restrict__ ei, bool is64,
                                          long long base, int e0, int n,
                                          bool al64, bool al32, int* out) {
    if (is64) {
        if (n == 4 && al64) {
            const int4 a = *reinterpret_cast<const int4*>(ei + 2 * (base + e0));
            const int4 b = *reinterpret_cast<const int4*>(ei + 2 * (base + e0) + 4);
            out[0] = a.x; out[1] = a.z; out[2] = b.x; out[3] = b.z;
        } else {
            for (int j = 0; j < n; ++j) out[j] = ei[2 * (base + e0 + j)];
        }
    } else {
        if (n == 4 && al32) {
            const int4 a = *reinterpret_cast<const int4*>(ei + base + e0);
            out[0] = a.x; out[1] = a.y; out[2] = a.z; out[3] = a.w;
        } else {
            for (int j = 0; j < n; ++j) out[j] = ei[base + e0 + j];
        }
    }
}

// blocks 0..63: zero indeg. blocks 64..79: split W1 -> w1t hi/lo (transposed
// [n][k]). blocks 80..87: split W2 -> w2t hi/lo.
__global__ __launch_bounds__(256) void k_init(int* __restrict__ indeg, int N,
                                              const float* __restrict__ W1,
                                              const float* __restrict__ W2,
                                              unsigned short* __restrict__ w1th,
                                              unsigned short* __restrict__ w1tl,
                                              unsigned short* __restrict__ w2th,
                                              unsigned short* __restrict__ w2tl) {
    const int b = blockIdx.x;
    if (b < 64) {
        const int i = b * 256 + threadIdx.x;
        const int n4 = N / 4;
        for (int j = i; j < n4; j += 64 * 256)
            reinterpret_cast<int4*>(indeg)[j] = make_int4(0, 0, 0, 0);
        const int tail = n4 * 4 + i;
        if (tail < N) indeg[tail] = 0;
    } else if (b < 80) {   // W1: 128x128 = 16384 elems, 16 blocks x 1024
        const int i = (b - 64) * 1024 + threadIdx.x * 4;
        const int n = i >> 7, k = i & 127;
#pragma unroll
        for (int j = 0; j < 4; ++j) {
            const float f = W1[(size_t)(k + j) * HID + n];
            const unsigned short h = f2bf_rne(f);
            w1th[n * 128 + k + j] = h;
            w1tl[n * 128 + k + j] = f2bf_rne(f - bf2f(h));
        }
    } else {               // W2: 128x64 = 8192 elems, 8 blocks x 1024
        const int i = (b - 80) * 1024 + threadIdx.x * 4;
        const int n = i >> 7, k = i & 127;
#pragma unroll
        for (int j = 0; j < 4; ++j) {
            const float f = W2[(size_t)(k + j) * OUT_CH + n];
            const unsigned short h = f2bf_rne(f);
            w2th[n * 128 + k + j] = h;
            w2tl[n * 128 + k + j] = f2bf_rne(f - bf2f(h));
        }
    }
}

__global__ void k_count(const int* __restrict__ ei, int* __restrict__ indeg, int E) {
    const bool is64 = probe_is64(ei);
    const bool al64 = (E % 2) == 0;
    const bool al32 = (E % 4) == 0;
    const int idx    = blockIdx.x * blockDim.x + threadIdx.x;
    const int stride = gridDim.x * blockDim.x;
    for (int e0 = idx * 4; e0 < E; e0 += stride * 4) {
        const int n = min(4, E - e0);
        int d[4];
        load_idx4(ei, is64, (long long)E, e0, n, al64, al32, d);
        for (int j = 0; j < n; ++j) atomicAdd(&indeg[d[j]], 1);
    }
}

__global__ __launch_bounds__(256) void k_scan1(const int* __restrict__ indeg,
                                               int* __restrict__ row_ptr,
                                               float* __restrict__ dinv,
                                               int* __restrict__ partials, int N) {
    const int t    = threadIdx.x;
    const int base = blockIdx.x * SCAN_CHUNK + t * 16;
    int v[16];
    if (base + 15 < N) {
        const int4* p = reinterpret_cast<const int4*>(indeg + base);
#pragma unroll
        for (int q = 0; q < 4; ++q) {
            const int4 a = p[q];
            v[q * 4 + 0] = a.x; v[q * 4 + 1] = a.y;
            v[q * 4 + 2] = a.z; v[q * 4 + 3] = a.w;
        }
    } else {
#pragma unroll
        for (int j = 0; j < 16; ++j)
            v[j] = (base + j < N) ? indeg[base + j] : 0;
    }
#pragma unroll
    for (int j = 0; j < 16; ++j)
        if (base + j < N) dinv[base + j] = rsqrtf((float)(v[j] + 1));

    int sum = 0;
#pragma unroll
    for (int j = 0; j < 16; ++j) { const int tv = v[j]; v[j] = sum; sum += tv; }

    int incl = sum;
#pragma unroll
    for (int off = 1; off < 64; off <<= 1) {
        int tt = __shfl_up(incl, off, 64);
        if ((t & 63) >= off) incl += tt;
    }
    __shared__ int wsum[4];
    if ((t & 63) == 63) wsum[t >> 6] = incl;
    __syncthreads();
    int woff = 0;
#pragma unroll
    for (int w = 0; w < 4; ++w) woff += (w < (t >> 6)) ? wsum[w] : 0;
    const int texcl = woff + incl - sum;

#pragma unroll
    for (int j = 0; j < 16; ++j)
        if (base + j < N) row_ptr[base + j] = texcl + v[j];
    if (t == 255) partials[blockIdx.x] = woff + incl;
}

__global__ __launch_bounds__(256) void k_scan3(const int* __restrict__ partials,
                                               int* __restrict__ row_ptr,
                                               int* __restrict__ cursor,
                                               int N, int nblk) {
    int off = 0;
    for (int w = 0; w < (int)blockIdx.x; ++w) off += partials[w];

    const int base = blockIdx.x * SCAN_CHUNK + threadIdx.x * 16;
    if (base + 15 < N) {
        int4* rp = reinterpret_cast<int4*>(row_ptr + base);
        int4* cp = reinterpret_cast<int4*>(cursor + base);
#pragma unroll
        for (int q = 0; q < 4; ++q) {
            int4 a = rp[q];
            a.x += off; a.y += off; a.z += off; a.w += off;
            rp[q] = a; cp[q] = a;
        }
    } else {
#pragma unroll
        for (int j = 0; j < 16; ++j) {
            const int i = base + j;
            if (i < N) { const int r = row_ptr[i] + off; row_ptr[i] = r; cursor[i] = r; }
        }
    }
    if ((int)blockIdx.x == nblk - 1 && threadIdx.x == 255)
        row_ptr[N] = off + partials[nblk - 1];
}

// MFMA GEMM1, LDS-free: h1b[M x 128](bf16) = x[M x 128](f32) @ W1.
// Split precision: acc += xh*wh + xl*wh + xh*wl (f32 accumulators).
// B-frags: short8 loads from pre-split transposed w1t (L1/L2-resident).
__device__ __forceinline__ void gemm1_mfma(const float* __restrict__ X,
                                           const unsigned short* __restrict__ w1th,
                                           const unsigned short* __restrict__ w1tl,
                                           unsigned short* __restrict__ Y,
                                           int M, int blk) {
    const int tid = threadIdx.x;
    const int wv  = tid >> 6;
    const int ln  = tid & 63;
    const int m16 = ln & 15;
    const int g   = ln >> 4;
    const int arow = blk * 64 + wv * 16 + m16;

    f32x4v acc[8];
#pragma unroll
    for (int n = 0; n < 8; ++n) acc[n] = {0.f, 0.f, 0.f, 0.f};

#pragma unroll
    for (int k0 = 0; k0 < 128; k0 += 32) {
        short8v ah, al;
        if (arow < M) {
            const float4 a0 = *reinterpret_cast<const float4*>(
                X + (size_t)arow * 128 + k0 + g * 8);
            const float4 a1 = *reinterpret_cast<const float4*>(
                X + (size_t)arow * 128 + k0 + g * 8 + 4);
            const float f[8] = {a0.x, a0.y, a0.z, a0.w, a1.x, a1.y, a1.z, a1.w};
#pragma unroll
            for (int e = 0; e < 8; ++e) {
                const unsigned short h = f2bf_rne(f[e]);
                ah[e] = (short)h;
                al[e] = (short)f2bf_rne(f[e] - bf2f(h));
            }
        } else {
#pragma unroll
            for (int e = 0; e < 8; ++e) { ah[e] = 0; al[e] = 0; }
        }

#pragma unroll
        for (int n = 0; n < 8; ++n) {
            const short8v bh = *reinterpret_cast<const short8v*>(
                w1th + (n * 16 + m16) * 128 + k0 + g * 8);
            const short8v bl = *reinterpret_cast<const short8v*>(
                w1tl + (n * 16 + m16) * 128 + k0 + g * 8);
            acc[n] = __builtin_amdgcn_mfma_f32_16x16x32_bf16(ah, bh, acc[n], 0, 0, 0);
            acc[n] = __builtin_amdgcn_mfma_f32_16x16x32_bf16(al, bh, acc[n], 0, 0, 0);
            acc[n] = __builtin_amdgcn_mfma_f32_16x16x32_bf16(ah, bl, acc[n], 0, 0, 0);
        }
    }

#pragma unroll
    for (int r = 0; r < 4; ++r) {
        const int orow = blk * 64 + wv * 16 + g * 4 + r;
        if (orow < M) {
#pragma unroll
            for (int n = 0; n < 8; ++n)
                Y[(size_t)orow * 128 + n * 16 + m16] = f2bf_rne(acc[n][r]);
        }
    }
}

// Dual-role dispatch; fill blocks first. Fill record = src only (4B store);
// dinv[src] is re-read (broadcast, L2) by the gathers.
__global__ __launch_bounds__(256) void k_fill_gemm1(
    const float* __restrict__ X, const unsigned short* __restrict__ w1th,
    const unsigned short* __restrict__ w1tl, unsigned short* __restrict__ Y,
    int M, int fillBlocks, const int* __restrict__ ei,
    int* __restrict__ cursor, int* __restrict__ csr_src, int E) {
    if ((int)blockIdx.x >= fillBlocks) {
        gemm1_mfma(X, w1th, w1tl, Y, M, blockIdx.x - fillBlocks);
    } else {
        const bool is64 = probe_is64(ei);
        const bool al64 = (E % 2) == 0;
        const bool al32 = (E % 4) == 0;
        const int nthr = fillBlocks * 256;
        const int idx  = blockIdx.x * 256 + threadIdx.x;
        for (int e0 = idx * 4; e0 < E; e0 += nthr * 4) {
            const int n = min(4, E - e0);
            int s[4], d[4];
            load_idx4(ei, is64, 0,            e0, n, true, true, s);
            load_idx4(ei, is64, (long long)E, e0, n, al64, al32, d);
            int pos[4];
            for (int j = 0; j < n; ++j) pos[j] = atomicAdd(&cursor[d[j]], 1);
            for (int j = 0; j < n; ++j) csr_src[pos[j]] = s[j];
        }
    }
}

// MFMA GEMM2, LDS-free: h2b[M x 64] = aggb[M x 128](bf16 exact) @ W2.
// Only W2 split: acc += a*wh + a*wl.
__global__ __launch_bounds__(256) void k_gemm2_mfma(
    const unsigned short* __restrict__ Xb, const unsigned short* __restrict__ w2th,
    const unsigned short* __restrict__ w2tl, unsigned short* __restrict__ Y, int M) {
    const int tid = threadIdx.x;
    const int wv  = tid >> 6;
    const int ln  = tid & 63;
    const int m16 = ln & 15;
    const int g   = ln >> 4;
    const int arow = blockIdx.x * 64 + wv * 16 + m16;

    f32x4v acc[4];
#pragma unroll
    for (int n = 0; n < 4; ++n) acc[n] = {0.f, 0.f, 0.f, 0.f};

#pragma unroll
    for (int k0 = 0; k0 < 128; k0 += 32) {
        short8v a;
        if (arow < M) {
            a = *reinterpret_cast<const short8v*>(Xb + (size_t)arow * 128 + k0 + g * 8);
        } else {
#pragma unroll
            for (int e = 0; e < 8; ++e) a[e] = 0;
        }
#pragma unroll
        for (int n = 0; n < 4; ++n) {
            const short8v bh = *reinterpret_cast<const short8v*>(
                w2th + (n * 16 + m16) * 128 + k0 + g * 8);
            const short8v bl = *reinterpret_cast<const short8v*>(
                w2tl + (n * 16 + m16) * 128 + k0 + g * 8);
            acc[n] = __builtin_amdgcn_mfma_f32_16x16x32_bf16(a, bh, acc[n], 0, 0, 0);
            acc[n] = __builtin_amdgcn_mfma_f32_16x16x32_bf16(a, bl, acc[n], 0, 0, 0);
        }
    }

#pragma unroll
    for (int r = 0; r < 4; ++r) {
        const int orow = blockIdx.x * 64 + wv * 16 + g * 4 + r;
        if (orow < M) {
#pragma unroll
            for (int n = 0; n < 4; ++n)
                Y[(size_t)orow * 64 + n * 16 + m16] = f2bf_rne(acc[n][r]);
        }
    }
}

// aggb[n](bf16) = relu(b1 + h[n]*dinv[n]^2 + sum_e h[s]*dinv[s]*dinv[n])
__global__ __launch_bounds__(256) void k_gather_relu(
    const unsigned short* __restrict__ h, const int* __restrict__ row_ptr,
    const int* __restrict__ csr_src, const float* __restrict__ dinv,
    const float* __restrict__ b, unsigned short* __restrict__ aggb, int N) {
    constexpr int LPN = HID / 4;   // 32
    const int tid  = blockIdx.x * blockDim.x + threadIdx.x;
    const int node = tid / LPN;
    const int lane = tid % LPN;
    if (node >= N) return;

    const float dn = dinv[node];
    float4 acc = reinterpret_cast<const float4*>(b)[lane];
    {
        const float w = dn * dn;
        const ushort4 v = *reinterpret_cast<const ushort4*>(h + (size_t)node * HID + lane * 4);
        acc.x = fmaf(bf2f(v.x), w, acc.x); acc.y = fmaf(bf2f(v.y), w, acc.y);
        acc.z = fmaf(bf2f(v.z), w, acc.z); acc.w = fmaf(bf2f(v.w), w, acc.w);
    }

    const int e1 = row_ptr[node + 1];
    int e = row_ptr[node];
    for (; e + 1 < e1; e += 2) {
        const int s0 = csr_src[e];
        const int s1 = csr_src[e + 1];
        const float w0 = dinv[s0] * dn;
        const float w1 = dinv[s1] * dn;
        const ushort4 v0 = *reinterpret_cast<const ushort4*>(h + (size_t)s0 * HID + lane * 4);
        const ushort4 v1 = *reinterpret_cast<const ushort4*>(h + (size_t)s1 * HID + lane * 4);
        acc.x = fmaf(bf2f(v0.x), w0, acc.x); acc.y = fmaf(bf2f(v0.y), w0, acc.y);
        acc.z = fmaf(bf2f(v0.z), w0, acc.z); acc.w = fmaf(bf2f(v0.w), w0, acc.w);
        acc.x = fmaf(bf2f(v1.x), w1, acc.x); acc.y = fmaf(bf2f(v1.y), w1, acc.y);
        acc.z = fmaf(bf2f(v1.z), w1, acc.z); acc.w = fmaf(bf2f(v1.w), w1, acc.w);
    }
    if (e < e1) {
        const int s0 = csr_src[e];
        const float w0 = dinv[s0] * dn;
        const ushort4 v0 = *reinterpret_cast<const ushort4*>(h + (size_t)s0 * HID + lane * 4);
        acc.x = fmaf(bf2f(v0.x), w0, acc.x); acc.y = fmaf(bf2f(v0.y), w0, acc.y);
        acc.z = fmaf(bf2f(v0.z), w0, acc.z); acc.w = fmaf(bf2f(v0.w), w0, acc.w);
    }

    ushort4 o;
    o.x = f2bf_rne(fmaxf(acc.x, 0.f));
    o.y = f2bf_rne(fmaxf(acc.y, 0.f));
    o.z = f2bf_rne(fmaxf(acc.z, 0.f));
    o.w = f2bf_rne(fmaxf(acc.w, 0.f));
    *reinterpret_cast<ushort4*>(aggb + (size_t)node * HID + lane * 4) = o;
}

// out[n](f32) = b + h[n]*dinv[n]^2 + sum_e h[s]*dinv[s]*dinv[n]
template <int C>
__global__ __launch_bounds__(256) void k_gather(const unsigned short* __restrict__ h,
                                                const int* __restrict__ row_ptr,
                                                const int* __restrict__ csr_src,
                                                const float* __restrict__ dinv,
                                                const float* __restrict__ b,
                                                float* __restrict__ out, int N) {
    constexpr int LPN = C / 4;
    const int tid  = blockIdx.x * blockDim.x + threadIdx.x;
    const int node = tid / LPN;
    const int lane = tid % LPN;
    if (node >= N) return;

    const float dn = dinv[node];
    float4 acc = reinterpret_cast<const float4*>(b)[lane];
    {
        const float w = dn * dn;
        const ushort4 v = *reinterpret_cast<const ushort4*>(h + (size_t)node * C + lane * 4);
        acc.x = fmaf(bf2f(v.x), w, acc.x); acc.y = fmaf(bf2f(v.y), w, acc.y);
        acc.z = fmaf(bf2f(v.z), w, acc.z); acc.w = fmaf(bf2f(v.w), w, acc.w);
    }

    const int e1 = row_ptr[node + 1];
    int e = row_ptr[node];
    for (; e + 1 < e1; e += 2) {
        const int s0 = csr_src[e];
        const int s1 = csr_src[e + 1];
        const float w0 = dinv[s0] * dn;
        const float w1 = dinv[s1] * dn;
        const ushort4 v0 = *reinterpret_cast<const ushort4*>(h + (size_t)s0 * C + lane * 4);
        const ushort4 v1 = *reinterpret_cast<const ushort4*>(h + (size_t)s1 * C + lane * 4);
        acc.x = fmaf(bf2f(v0.x), w0, acc.x); acc.y = fmaf(bf2f(v0.y), w0, acc.y);
        acc.z = fmaf(bf2f(v0.z), w0, acc.z); acc.w = fmaf(bf2f(v0.w), w0, acc.w);
        acc.x = fmaf(bf2f(v1.x), w1, acc.x); acc.y = fmaf(bf2f(v1.y), w1, acc.y);
        acc.z = fmaf(bf2f(v1.z), w1, acc.z); acc.w = fmaf(bf2f(v1.w), w1, acc.w);
    }
    if (e < e1) {
        const int s0 = csr_src[e];
        const float w0 = dinv[s0] * dn;
        const ushort4 v0 = *reinterpret_cast<const ushort4*>(h + (size_t)s0 * C + lane * 4);
        acc.x = fmaf(bf2f(v0.x), w0, acc.x); acc.y = fmaf(bf2f(v0.y), w0, acc.y);
        acc.z = fmaf(bf2f(v0.z), w0, acc.z); acc.w = fmaf(bf2f(v0.w), w0, acc.w);
    }

    reinterpret_cast<float4*>(out + (size_t)node * C)[lane] = acc;
}

extern "C" void kernel_launch(void* const* d_in, const int* in_sizes, int n_in,
                              void* d_out, int out_size, void* d_ws, size_t ws_size,
                              hipStream_t stream) {
    const float* x  = (const float*)d_in[0];
    const int*   ei = (const int*)d_in[1];
    const float* W1 = (const float*)d_in[2];
    const float* b1 = (const float*)d_in[3];
    const float* W2 = (const float*)d_in[4];
    const float* b2 = (const float*)d_in[5];
    float* out = (float*)d_out;

    const int N = in_sizes[0] / IN_CH;   // 50000
    const int E = in_sizes[1] / 2;       // 600000
    const int NBLK = (N + SCAN_CHUNK - 1) / SCAN_CHUNK;   // 13

    char* wsb = (char*)d_ws;
    size_t off = 0;
    auto alloc = [&](size_t bytes) -> void* {
        void* p = wsb + off;
        off += (bytes + 255) & ~(size_t)255;
        return p;
    };
    int*   indeg    = (int*)alloc((size_t)N * sizeof(int));
    int*   partials = (int*)alloc(64 * sizeof(int));
    float* dinv     = (float*)alloc((size_t)N * sizeof(float));
    int*   row_ptr  = (int*)alloc(((size_t)N + 1) * sizeof(int));
    int*   csr_src  = (int*)alloc((size_t)E * sizeof(int));
    unsigned short* w1th = (unsigned short*)alloc(128 * 128 * sizeof(unsigned short));
    unsigned short* w1tl = (unsigned short*)alloc(128 * 128 * sizeof(unsigned short));
    unsigned short* w2th = (unsigned short*)alloc(64 * 128 * sizeof(unsigned short));
    unsigned short* w2tl = (unsigned short*)alloc(64 * 128 * sizeof(unsigned short));
    unsigned short* h1b  = (unsigned short*)alloc((size_t)N * HID * sizeof(unsigned short));
    unsigned short* aggb = (unsigned short*)alloc((size_t)N * HID * sizeof(unsigned short));
    unsigned short* h2b  = (unsigned short*)alloc((size_t)N * OUT_CH * sizeof(unsigned short));
    int*   cursor   = indeg;   // indeg dead after k_scan1

    auto gs = [](long long n) { return (int)((n + 255) / 256); };

    k_init<<<88, 256, 0, stream>>>(indeg, N, W1, W2, w1th, w1tl, w2th, w2tl);
    k_count<<<gs((E + 3) / 4), 256, 0, stream>>>(ei, indeg, E);
    k_scan1<<<NBLK, 256, 0, stream>>>(indeg, row_ptr, dinv, partials, N);
    k_scan3<<<NBLK, 256, 0, stream>>>(partials, row_ptr, cursor, N, NBLK);

    // fill (first, long pole) || LDS-free MFMA gemm1
    const int fillBlocks = 1024;
    const int gemmBlocks = (N + 63) / 64;   // 782
    k_fill_gemm1<<<fillBlocks + gemmBlocks, 256, 0, stream>>>(
        x, w1th, w1tl, h1b, N, fillBlocks, ei, cursor, csr_src, E);

    // gather1 + bias + ReLU -> bf16 agg
    k_gather_relu<<<gs((long long)N * (HID / 4)), 256, 0, stream>>>(
        h1b, row_ptr, csr_src, dinv, b1, aggb, N);

    // layer 2 transform (LDS-free MFMA)
    k_gemm2_mfma<<<(N + 63) / 64, 256, 0, stream>>>(aggb, w2th, w2tl, h2b, N);

    // final gather + bias -> out (f32)
    k_gather<OUT_CH><<<gs((long long)N * (OUT_CH / 4)), 256, 0, stream>>>(
        h2b, row_ptr, csr_src, dinv, b2, out, N);
}